// Round 5
// baseline (3121.527 us; speedup 1.0000x reference)
//
#include <hip/hip_runtime.h>
#include <hip/hip_bf16.h>

#define NL 4
#define NB 4
#define NS 512
#define NH 1024
#define NV 32000
#define RING 16

typedef unsigned int u32;
typedef unsigned short u16;
typedef unsigned long long u64;
typedef __attribute__((ext_vector_type(8))) __bf16 vbf16x8;
typedef __attribute__((ext_vector_type(8))) u16   vu16x8;
typedef __attribute__((ext_vector_type(4))) u32   vu32x4;
typedef __attribute__((ext_vector_type(4))) float vf32x4;

__device__ __forceinline__ u16 f2bf(float f) {
    u32 x = __builtin_bit_cast(u32, f);
    x += 0x7FFFu + ((x >> 16) & 1u);
    return (u16)(x >> 16);
}
__device__ __forceinline__ float softplus_f(float x) {
    return fmaxf(x, 0.0f) + log1pf(expf(-fabsf(x)));
}
__device__ __forceinline__ int aloadi(const int* p) {
    return __hip_atomic_load(p, __ATOMIC_RELAXED, __HIP_MEMORY_SCOPE_AGENT);
}
__device__ __forceinline__ u64 aload64(const u64* p) {
    return __hip_atomic_load(p, __ATOMIC_RELAXED, __HIP_MEMORY_SCOPE_AGENT);
}
__device__ __forceinline__ void astorei(int* p, int v) {
    __hip_atomic_store(p, v, __ATOMIC_RELAXED, __HIP_MEMORY_SCOPE_AGENT);
}
__device__ __forceinline__ void astore32(u32* p, u32 v) {
    __hip_atomic_store(p, v, __ATOMIC_RELAXED, __HIP_MEMORY_SCOPE_AGENT);
}

#define APAD 8
#define ASTR (NH + APAD)

// 256 blocks x 256 threads. layer = bid&3, slice = bid>>2 (64 slices x 16 rows).
// Handshake: data stores -> vmcnt(0) -> ONE per-slice flag dword (value t+1).
// Consumers poll 64 slice-flags lane-parallel (1 load/lane/iter), then bulk-load data.
// Layer 3 publishes straight into the GEMM A buffer (full [B,S,H], no ring).
__global__ __launch_bounds__(256, 1) void lnn_recur(
    const int* __restrict__ ids, const float* __restrict__ emb,
    const float* __restrict__ Ws, const float* __restrict__ Us,
    const float* __restrict__ bsv, const float* __restrict__ twh,
    const float* __restrict__ twu, const float* __restrict__ tbv,
    const float* __restrict__ lambda_p,
    int* flags, int* ack, u32* ring, u32* out_dw, float* hT_out)
{
    __shared__ __align__(16) u16 act_hp[5][ASTR];   // rows 0-3 = batch, row 4 = zeros
    __shared__ __align__(16) u16 act_in[5][ASTR];
    __shared__ float cross[4][16][4];               // [mat][j][b]
    __shared__ float bias_a[16], bias_t[16];

    const int bid   = blockIdx.x;
    const int layer = bid & 3;
    const int slice = bid >> 2;
    const int j0    = slice << 4;
    const int tid   = threadIdx.x;
    const int wave  = tid >> 6;
    const int lane  = tid & 63;

    // ---- resident weight fragments: wave w owns matrix w (0=Ws,1=Us,2=twh,3=twu) ----
    const float* msel = (wave == 0) ? Ws : (wave == 1) ? Us : (wave == 2) ? twh : twu;
    const float* mat  = msel + (size_t)layer * NH * NH;
    const int jr = j0 + (lane & 15);        // B col = output row j
    const int kb = (lane >> 4) * 8;         // k offset within 32-chunk
    vbf16x8 wfrag[32];
#pragma unroll
    for (int c = 0; c < 32; ++c) {
        const float* s = mat + (size_t)jr * NH + c * 32 + kb;
        vu16x8 t8;
#pragma unroll
        for (int e = 0; e < 8; ++e) t8[e] = f2bf(s[e]);
        wfrag[c] = __builtin_bit_cast(vbf16x8, t8);
    }

    for (int i = tid; i < ASTR; i += 256) { act_hp[4][i] = 0; act_in[4][i] = 0; }
    if (tid < 16) {
        bias_a[tid] = bsv[layer * NH + j0 + tid];
        bias_t[tid] = tbv[layer * NH + j0 + tid];
    }
    const float lam = softplus_f(lambda_p[0]);
    float hreg = 0.0f;                       // wave0: (j = lane&15, b = lane>>4)
    const int lm1 = (layer > 0) ? layer - 1 : 0;

    for (int t = 0; t < NS; ++t) {
        const int b     = wave;
        const int slotH = (t - 1) & (RING - 1);
        const int slotI = t & (RING - 1);
        u64 hq[4], iq[4];

        // layer 0: emb gather + pack BEFORE polling (overlaps detect latency)
        if (layer == 0) {
            const int v = ids[b * NS + t];
            const float* er = emb + (size_t)v * NH;
#pragma unroll
            for (int q = 0; q < 4; ++q) {
                vf32x4 f = *(const vf32x4*)(er + 4 * (lane + 64 * q));
                u32 lo = (u32)f2bf(f[0]) | ((u32)f2bf(f[1]) << 16);
                u32 hi = (u32)f2bf(f[2]) | ((u32)f2bf(f[3]) << 16);
                iq[q] = (u64)lo | ((u64)hi << 32);
            }
        }

        // ---- A: poll per-slice flags (lane-parallel, 1-3 dwords/lane/iter) ----
        {
            const bool needH = (t > 0);
            const bool needI = (layer > 0);
            const int* fH = flags + ((layer << 4) + slotH) * 64 + lane;
            const int* fI = flags + ((lm1   << 4) + slotI) * 64 + lane;
            const bool needAck = (layer < 3) && (t >= RING);
            const int  ackTgt  = t - RING + 1;
            const int* ackp    = ack + (layer + 1) * 64 + lane;
            bool ackok = !needAck;
            for (int it = 0; it < (1 << 20); ++it) {
                bool ok = true;
                if (needH) ok &= (aloadi(fH) >= t);
                if (needI) ok &= (aloadi(fI) >= t + 1);
                if (!ackok) ackok = (aloadi(ackp) >= ackTgt);
                ok &= ackok;
                if (__all((int)ok)) break;
                __builtin_amdgcn_s_sleep(1);
            }
        }

        // ---- B: bulk data load (all in flight), stage to LDS ----
        if (layer > 0) {
            const u64* ir = (const u64*)(ring + (((size_t)(lm1 * NB + b)) * RING + slotI) * 512);
#pragma unroll
            for (int q = 0; q < 4; ++q) iq[q] = aload64(ir + lane + 64 * q);
        }
        if (t == 0) {
            hq[0] = hq[1] = hq[2] = hq[3] = 0;
        } else {
            const u64* hr = (layer == 3)
                ? (const u64*)(out_dw + ((size_t)b * NS + (t - 1)) * 512)
                : (const u64*)(ring + (((size_t)(layer * NB + b)) * RING + slotH) * 512);
#pragma unroll
            for (int q = 0; q < 4; ++q) hq[q] = aload64(hr + lane + 64 * q);
        }
        {
            u64* dh = (u64*)&act_hp[b][0];
            u64* di = (u64*)&act_in[b][0];
#pragma unroll
            for (int q = 0; q < 4; ++q) { dh[lane + 64 * q] = hq[q]; di[lane + 64 * q] = iq[q]; }
        }
        __syncthreads();
        if (tid == 0 && layer > 0) astorei(ack + layer * 64 + slice, t + 1);   // consumed in(t)

        // ---- C: MFMA out[j,b] = sum_k act[b,k] * M[j,k]; 4 accumulators ----
        {
            const u16 (*asrc)[ASTR] = ((wave & 1) == 0) ? act_hp : act_in;
            int ar = lane & 15; if (ar > 4) ar = 4;   // rows 5-15 read the zero row
            vf32x4 a0 = {0.f,0.f,0.f,0.f}, a1 = a0, a2 = a0, a3 = a0;
#pragma unroll
            for (int c = 0; c < 32; c += 4) {
                a0 = __builtin_amdgcn_mfma_f32_16x16x32_bf16(*(const vbf16x8*)&asrc[ar][(c+0)*32+kb], wfrag[c+0], a0, 0, 0, 0);
                a1 = __builtin_amdgcn_mfma_f32_16x16x32_bf16(*(const vbf16x8*)&asrc[ar][(c+1)*32+kb], wfrag[c+1], a1, 0, 0, 0);
                a2 = __builtin_amdgcn_mfma_f32_16x16x32_bf16(*(const vbf16x8*)&asrc[ar][(c+2)*32+kb], wfrag[c+2], a2, 0, 0, 0);
                a3 = __builtin_amdgcn_mfma_f32_16x16x32_bf16(*(const vbf16x8*)&asrc[ar][(c+3)*32+kb], wfrag[c+3], a3, 0, 0, 0);
            }
            vf32x4 acc = (a0 + a1) + (a2 + a3);
            if (lane < 16) {
#pragma unroll
                for (int r = 0; r < 4; ++r) cross[wave][lane][r] = acc[r];
            }
        }
        __syncthreads();

        // ---- D: finalize + publish (wave 0): data -> vmcnt(0) -> flag -> extras ----
        if (wave == 0) {
            const int j = lane & 15, bb = lane >> 4;
            const float sa = cross[0][j][bb] + cross[1][j][bb] + bias_a[j];
            const float st = cross[2][j][bb] + cross[3][j][bb] + bias_t[j];
            const float tau = softplus_f(st) + 0.01f;
            const float av  = tanhf(sa);
            float dx = lam * (av - hreg / tau);
            dx = fminf(10.0f, fmaxf(-10.0f, dx));
            hreg = fmaf(0.1f, dx, hreg);
            const u16 hb = f2bf(hreg);
            const u32 up = (u32)__shfl_down((int)hb, 1);
            const u32 pk = (u32)hb | (up << 16);
            u32* rowp = (layer == 3)
                ? out_dw + ((size_t)bb * NS + t) * 512
                : ring + (((size_t)(layer * NB + bb)) * RING + slotI) * 512;
            if ((lane & 1) == 0) astore32(rowp + ((j0 + j) >> 1), pk);
            asm volatile("s_waitcnt vmcnt(0)" ::: "memory");
            if (lane == 0) astorei(flags + ((layer << 4) + slotI) * 64 + slice, t + 1);
            if (t == NS - 1) hT_out[((size_t)layer * NB + bb) * NH + j0 + j] = hreg;   // off path
        }
    }
}

// ---------------- projection GEMM: C[2048][32000] = A[2048][1024](bf16) * W[32000][1024]^T + b ----
#define BM 128
#define BN 128
#define BK 32
#define KSTEPS (NH / BK)
#define LSTR (BK + 8)

__global__ __launch_bounds__(256, 1) void proj_gemm(
    const u16* __restrict__ A, const float* __restrict__ Bw,
    const float* __restrict__ bias, float* __restrict__ C)
{
    __shared__ __align__(16) u16 Asm[2][BM][LSTR];
    __shared__ __align__(16) u16 Bsm[2][BN][LSTR];

    const int tid  = threadIdx.x;
    const int wave = tid >> 6, lane = tid & 63;
    const int wr = wave >> 1, wc = wave & 1;

    const int nwg = gridDim.x;
    const int id  = blockIdx.x;
    const int q = nwg >> 3, r = nwg & 7;
    const int x = id & 7, o = id >> 3;
    const int wg = (x < r ? x * (q + 1) : r * (q + 1) + (x - r) * q) + o;
    const int m0 = (wg & 15) * BM;
    const int n0 = (wg >> 4) * BN;

    const int srow  = tid >> 1;
    const int shalf = tid & 1;
    const u16*   agp = A  + (size_t)(m0 + srow) * NH + shalf * 16;
    const float* bgp = Bw + (size_t)(n0 + srow) * NH + shalf * 16;

    vf32x4 zed = {0.f, 0.f, 0.f, 0.f};
    vf32x4 acc[4][4];
#pragma unroll
    for (int m = 0; m < 4; ++m)
#pragma unroll
        for (int n = 0; n < 4; ++n) acc[m][n] = zed;

    vu32x4 areg0, areg1; vf32x4 breg0, breg1, breg2, breg3;
    auto load_tile = [&](int kt) {
        const u16* ap = agp + kt * BK;
        areg0 = *(const vu32x4*)ap;
        areg1 = *(const vu32x4*)(ap + 8);
        const float* bp = bgp + kt * BK;
        breg0 = *(const vf32x4*)bp;       breg1 = *(const vf32x4*)(bp + 4);
        breg2 = *(const vf32x4*)(bp + 8); breg3 = *(const vf32x4*)(bp + 12);
    };
    auto write_tile = [&](int buf) {
        u16* ad = &Asm[buf][srow][shalf * 16];
        *(vu32x4*)ad = areg0; *(vu32x4*)(ad + 8) = areg1;
        float fb[16];
        *(vf32x4*)&fb[0] = breg0; *(vf32x4*)&fb[4]  = breg1;
        *(vf32x4*)&fb[8] = breg2; *(vf32x4*)&fb[12] = breg3;
        vu16x8 v0, v1;
#pragma unroll
        for (int e = 0; e < 8; ++e) { v0[e] = f2bf(fb[e]); v1[e] = f2bf(fb[8 + e]); }
        u16* bd = &Bsm[buf][srow][shalf * 16];
        *(vu16x8*)bd = v0; *(vu16x8*)(bd + 8) = v1;
    };

    load_tile(0); write_tile(0);
    __syncthreads();

    const int fr = lane & 15;
    const int fk = (lane >> 4) * 8;
    for (int kt = 0; kt < KSTEPS; ++kt) {
        const int cur = kt & 1;
        if (kt + 1 < KSTEPS) load_tile(kt + 1);
        vbf16x8 afr[4], bfr[4];
#pragma unroll
        for (int m = 0; m < 4; ++m)
            afr[m] = *(const vbf16x8*)&Asm[cur][wr * 64 + m * 16 + fr][fk];
#pragma unroll
        for (int n = 0; n < 4; ++n)
            bfr[n] = *(const vbf16x8*)&Bsm[cur][wc * 64 + n * 16 + fr][fk];
#pragma unroll
        for (int m = 0; m < 4; ++m)
#pragma unroll
            for (int n = 0; n < 4; ++n)
                acc[m][n] = __builtin_amdgcn_mfma_f32_16x16x32_bf16(afr[m], bfr[n], acc[m][n], 0, 0, 0);
        if (kt + 1 < KSTEPS) write_tile(cur ^ 1);
        __syncthreads();
    }

    const int cc = lane & 15;
    const int cr = (lane >> 4) * 4;
#pragma unroll
    for (int m = 0; m < 4; ++m) {
#pragma unroll
        for (int n = 0; n < 4; ++n) {
            const int gc = n0 + wc * 64 + n * 16 + cc;
            const float bval = bias[gc];
            float* cp = C + (size_t)(m0 + wr * 64 + m * 16 + cr) * NV + gc;
#pragma unroll
            for (int r = 0; r < 4; ++r)
                cp[(size_t)r * NV] = acc[m][n][r] + bval;
        }
    }
}

extern "C" void kernel_launch(void* const* d_in, const int* in_sizes, int n_in,
                              void* d_out, int out_size, void* d_ws, size_t ws_size,
                              hipStream_t stream) {
    const int*   ids = (const int*)  d_in[0];
    const float* emb = (const float*)d_in[1];
    const float* pw  = (const float*)d_in[2];
    const float* pb  = (const float*)d_in[3];
    const float* lam = (const float*)d_in[4];
    const float* Ws  = (const float*)d_in[5];
    const float* Us  = (const float*)d_in[6];
    const float* bsv = (const float*)d_in[7];
    const float* twh = (const float*)d_in[8];
    const float* twu = (const float*)d_in[9];
    const float* tbv = (const float*)d_in[10];

    char* ws = (char*)d_ws;
    int* flags  = (int*)ws;                             // 4*16*64*4 = 16 KB
    int* ack    = (int*)(ws + 16384);                   // 4*64*4 = 1 KB (pad to 4 KB)
    u32* ring   = (u32*)(ws + 20480);                   // 4*4*16*512*4 = 512 KB (layer 3 unused)
    u32* out_dw = (u32*)(ws + 20480 + 524288);          // 2048*512*4 = 4 MB

    float* logits = (float*)d_out;
    float* hT     = logits + (size_t)NB * NS * NV;

    hipMemsetAsync(ws, 0, 20480, stream);               // flags + acks, every call
    lnn_recur<<<dim3(256), dim3(256), 0, stream>>>(ids, emb, Ws, Us, bsv, twh, twu, tbv, lam,
                                                   flags, ack, ring, out_dw, hT);
    proj_gemm<<<dim3((NV / BN) * ((NB * NS) / BM)), dim3(256), 0, stream>>>(
        (const u16*)out_dw, pw, pb, logits);
}